// Round 4
// baseline (432.659 us; speedup 1.0000x reference)
//
#include <hip/hip_runtime.h>
#include <math.h>

typedef __bf16 bf16;
typedef __bf16 bf16x4 __attribute__((ext_vector_type(4)));
typedef __bf16 bf16x8 __attribute__((ext_vector_type(8)));
typedef float f32x16 __attribute__((ext_vector_type(16)));

#define MODE_QK     0
#define MODE_V      1
#define MODE_SCORES 2
#define MODE_PV     3

__device__ inline void gload_lds16(const bf16* g, bf16* l) {
    __builtin_amdgcn_global_load_lds(
        (const __attribute__((address_space(1))) void*)g,
        (__attribute__((address_space(3))) void*)l, 16, 0, 0);
}

// NT GEMM, 128x128 tile, BK=32, 4 waves, bf16 in, MFMA 32x32x16.
// LDS layout is K-MAJOR in 16B chunks: chunk(k8, row) lives at (k8*128+row)*8 elems,
// k8 = k/8 (0..3). Fragment reads then span all 32 banks -> conflict-free.
// A/B fragment: m(or n)=lane&31, k = kstep*16 + (lane>>5)*8 + j.
// C/D: col=lane&31, row=(reg&3)+8*(reg>>2)+4*(lane>>5)  [m74/m101-verified]
template <int MODE>
__global__ __launch_bounds__(256) void mfma_nt(
    const bf16* __restrict__ A, const bf16* __restrict__ B,
    const float* __restrict__ bias, void* __restrict__ Cv,
    bf16* __restrict__ Vt, float* __restrict__ lsum,
    int K, int lda, int ldb, int ldc,
    long sA, long sB, long sC, float alpha)
{
    A += (long)blockIdx.z * sA;
    B += (long)blockIdx.z * sB;
    char* Cb = (char*)Cv + (long)blockIdx.z * sC;
    if constexpr (MODE == MODE_SCORES || MODE == MODE_PV)
        lsum += (long)blockIdx.z * 2048;

    __shared__ bf16 As[128 * 32] __attribute__((aligned(16)));
    __shared__ bf16 Bs[128 * 32] __attribute__((aligned(16)));

    const int t  = threadIdx.x;
    const int m0 = blockIdx.y * 128;
    const int n0 = blockIdx.x * 128;

    const int lane = t & 63;
    const int wave = t >> 6;
    const int wrow = (wave >> 1) * 64;
    const int wcol = (wave & 1) * 64;
    const int lm   = lane & 31;          // m/n within a 32-frag
    const int khl  = lane >> 5;          // which 8-k half this lane holds

    // staging: lds chunk c holds global chunk (row=c&127, k8=c>>7)
    const int sr0 = t & 127,        sk0 = (t >> 7) * 8;        // i=0: c=t
    const int sr1 = t & 127,        sk1 = ((t + 256) >> 7) * 8; // i=1: c=t+256

    f32x16 acc[2][2] = {};

    for (int k0 = 0; k0 < K; k0 += 32) {
        gload_lds16(A + (long)(m0 + sr0) * lda + k0 + sk0, &As[t * 8]);
        gload_lds16(A + (long)(m0 + sr1) * lda + k0 + sk1, &As[(t + 256) * 8]);
        gload_lds16(B + (long)(n0 + sr0) * ldb + k0 + sk0, &Bs[t * 8]);
        gload_lds16(B + (long)(n0 + sr1) * ldb + k0 + sk1, &Bs[(t + 256) * 8]);
        __syncthreads();

        bf16x8 af[2][2], bf[2][2];   // [kstep][subtile]
#pragma unroll
        for (int ks = 0; ks < 2; ks++) {
            const int kc = (ks * 2 + khl) * 128;   // chunk row base for this k-half
#pragma unroll
            for (int i = 0; i < 2; i++) {
                af[ks][i] = *(const bf16x8*)&As[(kc + wrow + i * 32 + lm) * 8];
                bf[ks][i] = *(const bf16x8*)&Bs[(kc + wcol + i * 32 + lm) * 8];
            }
        }
#pragma unroll
        for (int ks = 0; ks < 2; ks++)
#pragma unroll
            for (int i = 0; i < 2; i++)
#pragma unroll
                for (int j = 0; j < 2; j++)
                    acc[i][j] = __builtin_amdgcn_mfma_f32_32x32x16_bf16(
                        af[ks][i], bf[ks][j], acc[i][j], 0, 0, 0);
        __syncthreads();
    }

    const int rb = 4 * khl;   // row base from lane half

    if constexpr (MODE == MODE_QK) {
        bf16* C = (bf16*)Cb;
#pragma unroll
        for (int j = 0; j < 2; j++) {
            const int col = n0 + wcol + j * 32 + lm;
            const float bv = bias[col];
#pragma unroll
            for (int i = 0; i < 2; i++) {
                const int base = m0 + wrow + i * 32 + rb;
#pragma unroll
                for (int reg = 0; reg < 16; reg++) {
                    const long row = base + (reg & 3) + 8 * (reg >> 2);
                    C[row * ldc + col] = (bf16)(acc[i][j][reg] + bv);
                }
            }
        }
    } else if constexpr (MODE == MODE_V) {
        // cols are V features e (bias pre-offset at launch); write Vt[b][e][s]
#pragma unroll
        for (int j = 0; j < 2; j++) {
            const int e = n0 + wcol + j * 32 + lm;
            const float bv = bias[e];
#pragma unroll
            for (int i = 0; i < 2; i++) {
                const int srow = m0 + wrow + i * 32 + rb;
                const int b = srow >> 11, s = srow & 2047;
#pragma unroll
                for (int q = 0; q < 4; q++) {
                    bf16x4 pk;
#pragma unroll
                    for (int r = 0; r < 4; r++)
                        pk[r] = (bf16)(acc[i][j][q * 4 + r] + bv);
                    *(bf16x4*)(Vt + ((long)b * 1024 + e) * 2048 + s + 8 * q) = pk;
                }
            }
        }
    } else if constexpr (MODE == MODE_SCORES) {
        bf16* C = (bf16*)Cb;
        float rsum[2][16];
#pragma unroll
        for (int i = 0; i < 2; i++)
#pragma unroll
            for (int reg = 0; reg < 16; reg++) rsum[i][reg] = 0.f;
#pragma unroll
        for (int j = 0; j < 2; j++) {
            const int col = n0 + wcol + j * 32 + lm;
#pragma unroll
            for (int i = 0; i < 2; i++) {
                const int base = m0 + wrow + i * 32 + rb;
#pragma unroll
                for (int reg = 0; reg < 16; reg++) {
                    const long row = base + (reg & 3) + 8 * (reg >> 2);
                    const float e = __expf(alpha * acc[i][j][reg]);
                    C[row * ldc + col] = (bf16)e;
                    rsum[i][reg] += e;
                }
            }
        }
        // reduce across the 32 col-lanes (xor of low 5 bits keeps lane-half)
#pragma unroll
        for (int off = 1; off < 32; off <<= 1)
#pragma unroll
            for (int i = 0; i < 2; i++)
#pragma unroll
                for (int reg = 0; reg < 16; reg++)
                    rsum[i][reg] += __shfl_xor(rsum[i][reg], off);
        if (lm == 0) {
#pragma unroll
            for (int i = 0; i < 2; i++) {
                const int base = m0 + wrow + i * 32 + rb;
#pragma unroll
                for (int reg = 0; reg < 16; reg++)
                    atomicAdd(&lsum[base + (reg & 3) + 8 * (reg >> 2)], rsum[i][reg]);
            }
        }
    } else {  // MODE_PV
        float* C = (float*)Cb;
        float linv[2][16];
#pragma unroll
        for (int i = 0; i < 2; i++) {
            const int base = m0 + wrow + i * 32 + rb;
#pragma unroll
            for (int reg = 0; reg < 16; reg++)
                linv[i][reg] = 1.0f / lsum[base + (reg & 3) + 8 * (reg >> 2)];
        }
#pragma unroll
        for (int j = 0; j < 2; j++) {
            const int col = n0 + wcol + j * 32 + lm;
#pragma unroll
            for (int i = 0; i < 2; i++) {
                const int base = m0 + wrow + i * 32 + rb;
#pragma unroll
                for (int reg = 0; reg < 16; reg++) {
                    const long row = base + (reg & 3) + 8 * (reg >> 2);
                    C[row * ldc + col] = acc[i][j][reg] * linv[i][reg];
                }
            }
        }
    }
}

__global__ __launch_bounds__(256) void f32_to_bf16(
    const float* __restrict__ in, bf16* __restrict__ out, long n)
{
    long i = ((long)blockIdx.x * 256 + threadIdx.x) * 4;
    if (i < n) {
        float4 v = *(const float4*)(in + i);
        bf16x4 o = { (bf16)v.x, (bf16)v.y, (bf16)v.z, (bf16)v.w };
        *(bf16x4*)(out + i) = o;
    }
}

// out1[row] = fp32(Pu[row]) / l[row]; one block per row, 2048 cols.
__global__ __launch_bounds__(256) void normalize_rows(
    const bf16* __restrict__ Pu, const float* __restrict__ l,
    float* __restrict__ out1)
{
    const long row = blockIdx.x;
    const float inv = 1.0f / l[row];
    const bf16* p = Pu + row * 2048;
    float* o = out1 + row * 2048;
    const int t = threadIdx.x;
    bf16x8 v = *(const bf16x8*)(p + t * 8);
    float4 a, b;
    a.x = (float)v[0] * inv; a.y = (float)v[1] * inv;
    a.z = (float)v[2] * inv; a.w = (float)v[3] * inv;
    b.x = (float)v[4] * inv; b.y = (float)v[5] * inv;
    b.z = (float)v[6] * inv; b.w = (float)v[7] * inv;
    *(float4*)(o + t * 8)     = a;
    *(float4*)(o + t * 8 + 4) = b;
}

extern "C" void kernel_launch(void* const* d_in, const int* in_sizes, int n_in,
                              void* d_out, int out_size, void* d_ws, size_t ws_size,
                              hipStream_t stream)
{
    const int B = 4, S = 2048, E = 1024;
    const float* X    = (const float*)d_in[0];   // [B,S,E]
    const float* W    = (const float*)d_in[1];   // [3E,E]
    const float* bias = (const float*)d_in[2];   // [3E]

    float* out0 = (float*)d_out;                  // [B,S,E]
    float* out1 = out0 + (long)B * S * E;         // [B,S,S]

    // ws layout (bytes):
    //   [ 0M, 32M)  QKb  bf16 [B*S, 2048]
    //   [32M, 48M)  Vt   bf16 [B][E][S]
    //   [48M, 80M)  Pu   bf16 [B][S][S]
    //   [80M, +32K) l    fp32 [B*S]
    //   Xb/Wb overlap Pu (dead before Pu written)
    char* ws = (char*)d_ws;
    bf16* QKb = (bf16*)(ws);
    bf16* Vt  = (bf16*)(ws + 33554432);
    bf16* Pu  = (bf16*)(ws + 50331648);
    float* l  = (float*)(ws + 83886080);
    bf16* Xb  = (bf16*)(ws + 50331648);
    bf16* Wb  = (bf16*)(ws + 67108864);

    f32_to_bf16<<<(long)B * S * E / 1024, 256, 0, stream>>>(X, Xb, (long)B * S * E);
    f32_to_bf16<<<(long)3 * E * E / 1024, 256, 0, stream>>>(W, Wb, (long)3 * E * E);
    hipMemsetAsync(l, 0, (long)B * S * sizeof(float), stream);

    // QK projection: [B*S,2048] = X @ W[0:2048]^T + b
    mfma_nt<MODE_QK><<<dim3(2048 / 128, B * S / 128, 1), 256, 0, stream>>>(
        Xb, Wb, bias, QKb, nullptr, nullptr,
        E, E, E, 2048, 0, 0, 0, 1.0f);

    // V projection (transposed store): Vt[b][e][s] = (X @ W[2048:3072]^T + b)^T
    mfma_nt<MODE_V><<<dim3(1024 / 128, B * S / 128, 1), 256, 0, stream>>>(
        Xb, Wb + (long)2048 * 1024, bias + 2048, nullptr, Vt, nullptr,
        E, E, E, 0, 0, 0, 0, 1.0f);

    // Pu = exp(Q @ K^T / 32) (bf16) + row sums l
    mfma_nt<MODE_SCORES><<<dim3(S / 128, S / 128, B), 256, 0, stream>>>(
        QKb, QKb + 1024, nullptr, Pu, nullptr, l,
        E, 2048, 2048, S,
        (long)S * 2048, (long)S * 2048, (long)S * S * 2, 0.03125f);

    // out1 = Pu / l
    normalize_rows<<<B * S, 256, 0, stream>>>(Pu, l, out1);

    // out0 = (Pu @ V) / l
    mfma_nt<MODE_PV><<<dim3(E / 128, S / 128, B), 256, 0, stream>>>(
        Pu, Vt, nullptr, out0, nullptr, l,
        S, S, S, E,
        (long)S * S, (long)E * S, (long)S * E * 4, 1.0f);
}

// Round 5
// 344.321 us; speedup vs baseline: 1.2566x; 1.2566x over previous
//
#include <hip/hip_runtime.h>
#include <math.h>

typedef __bf16 bf16;
typedef __bf16 bf16x4 __attribute__((ext_vector_type(4)));
typedef __bf16 bf16x8 __attribute__((ext_vector_type(8)));
typedef float f32x4 __attribute__((ext_vector_type(4)));

#define MODE_QKV    0
#define MODE_SCORES 1
#define MODE_PV     2

__device__ inline void gload_lds16(const bf16* g, bf16* l) {
    __builtin_amdgcn_global_load_lds(
        (const __attribute__((address_space(1))) void*)g,
        (__attribute__((address_space(3))) void*)l, 16, 0, 0);
}

// NT GEMM, 128x128 tile, BK=32, 4 waves, MFMA 16x16x32 (R2-proven core).
// LDS chunk (r,q) holds global 16B chunk (row=r, k8 = q ^ ((r>>1)&3)):
// same 64B global lines per 4-lane group as row-major (coalescing unchanged),
// but fragment reads spread to 2-way-per-bank (free) instead of ~8-way.
// MODE_QKV:    C = bf16(acc + bias[col])
// MODE_SCORES: C = bf16(exp(alpha*acc))
// MODE_PV:     C = fp32 acc
template <int MODE>
__global__ __launch_bounds__(256) void mfma_nt(
    const bf16* __restrict__ A, const bf16* __restrict__ B,
    const float* __restrict__ bias, void* __restrict__ Cv,
    int K, int lda, int ldb, int ldc,
    long sA, long sB, long sC, float alpha)
{
    A += (long)blockIdx.z * sA;
    B += (long)blockIdx.z * sB;

    __shared__ bf16 As[128 * 32] __attribute__((aligned(16)));
    __shared__ bf16 Bs[128 * 32] __attribute__((aligned(16)));

    const int t  = threadIdx.x;
    const int m0 = blockIdx.y * 128;
    const int n0 = blockIdx.x * 128;

    const int lane = t & 63;
    const int wave = t >> 6;
    const int wrow = (wave >> 1) * 64;
    const int wcol = (wave & 1) * 64;
    const int fr   = lane & 15;
    const int kq8  = lane >> 4;          // which 8-k chunk this lane's quad wants

    // staging: chunk index c -> row r=c>>2, slot q=c&3, global k8 = q ^ ((r>>1)&3)
    const int r0 = t >> 2,         q0 = t & 3;
    const int r1 = (t + 256) >> 2, q1 = (t + 256) & 3;
    const int k80 = (q0 ^ ((r0 >> 1) & 3)) * 8;
    const int k81 = (q1 ^ ((r1 >> 1) & 3)) * 8;

    f32x4 acc[4][4] = {};

    for (int k0 = 0; k0 < K; k0 += 32) {
        gload_lds16(A + (long)(m0 + r0) * lda + k0 + k80, &As[t * 8]);
        gload_lds16(A + (long)(m0 + r1) * lda + k0 + k81, &As[(t + 256) * 8]);
        gload_lds16(B + (long)(n0 + r0) * ldb + k0 + k80, &Bs[t * 8]);
        gload_lds16(B + (long)(n0 + r1) * ldb + k0 + k81, &Bs[(t + 256) * 8]);
        __syncthreads();

        bf16x8 af[4], bfr[4];
#pragma unroll
        for (int i = 0; i < 4; i++) {
            const int ra = wrow + i * 16 + fr;
            const int rb = wcol + i * 16 + fr;
            af[i]  = *(const bf16x8*)&As[(ra * 4 + (kq8 ^ ((ra >> 1) & 3))) * 8];
            bfr[i] = *(const bf16x8*)&Bs[(rb * 4 + (kq8 ^ ((rb >> 1) & 3))) * 8];
        }
#pragma unroll
        for (int i = 0; i < 4; i++)
#pragma unroll
            for (int j = 0; j < 4; j++)
                acc[i][j] = __builtin_amdgcn_mfma_f32_16x16x32_bf16(
                    af[i], bfr[j], acc[i][j], 0, 0, 0);
        __syncthreads();
    }

    // C/D layout: col=lane&15, row=(lane>>4)*4+reg  [m89-verified]
    const int r4 = (lane >> 4) * 4;
    if constexpr (MODE == MODE_PV) {
        float* C = (float*)Cv + (long)blockIdx.z * sC;
#pragma unroll
        for (int j = 0; j < 4; j++) {
            const int col = n0 + wcol + j * 16 + fr;
#pragma unroll
            for (int i = 0; i < 4; i++)
#pragma unroll
                for (int r = 0; r < 4; r++) {
                    const long row = m0 + wrow + i * 16 + r4 + r;
                    C[row * ldc + col] = acc[i][j][r];
                }
        }
    } else {
        bf16* C = (bf16*)Cv + (long)blockIdx.z * sC;
#pragma unroll
        for (int j = 0; j < 4; j++) {
            const int col = n0 + wcol + j * 16 + fr;
            const float bv = (MODE == MODE_QKV) ? bias[col] : 0.f;
#pragma unroll
            for (int i = 0; i < 4; i++)
#pragma unroll
                for (int r = 0; r < 4; r++) {
                    const long row = m0 + wrow + i * 16 + r4 + r;
                    float v = acc[i][j][r];
                    if constexpr (MODE == MODE_QKV)
                        C[row * ldc + col] = (bf16)(v + bv);
                    else
                        C[row * ldc + col] = (bf16)__expf(alpha * v);
                }
        }
    }
}

__global__ __launch_bounds__(256) void f32_to_bf16(
    const float* __restrict__ in, bf16* __restrict__ out, long n)
{
    long i = ((long)blockIdx.x * 256 + threadIdx.x) * 4;
    if (i < n) {
        float4 v = *(const float4*)(in + i);
        bf16x4 o = { (bf16)v.x, (bf16)v.y, (bf16)v.z, (bf16)v.w };
        *(bf16x4*)(out + i) = o;
    }
}

// Vt[b][e][s] = V[b][s][e]; V has ld 3072 (inside qkv), Vt ld 2048.
__global__ __launch_bounds__(256) void transpose_v(
    const bf16* __restrict__ V, bf16* __restrict__ Vt)
{
    __shared__ bf16 tile[32][33];
    const bf16* Vb  = V  + (long)blockIdx.z * 2048 * 3072;
    bf16*       Vtb = Vt + (long)blockIdx.z * 1024 * 2048;
    const int s0 = blockIdx.x * 32, e0 = blockIdx.y * 32;
    const int tx = threadIdx.x & 31, ty = threadIdx.x >> 5;
#pragma unroll
    for (int i = 0; i < 32; i += 8)
        tile[ty + i][tx] = Vb[(long)(s0 + ty + i) * 3072 + e0 + tx];
    __syncthreads();
#pragma unroll
    for (int i = 0; i < 32; i += 8)
        Vtb[(long)(e0 + ty + i) * 2048 + s0 + tx] = tile[tx][ty + i];
}

// Per row: sum exp-scores, write fp32 out1 = Pu/l, renormalize Pu IN PLACE (bf16).
__global__ __launch_bounds__(256) void norm_rows(
    bf16* __restrict__ Pu, float* __restrict__ out1)
{
    bf16* p  = Pu   + (long)blockIdx.x * 2048;
    float* o = out1 + (long)blockIdx.x * 2048;
    const int t = threadIdx.x;
    bf16x8 v = *(const bf16x8*)(p + t * 8);
    float f[8];
    float s = 0.f;
#pragma unroll
    for (int k = 0; k < 8; k++) { f[k] = (float)v[k]; s += f[k]; }
#pragma unroll
    for (int off = 32; off > 0; off >>= 1) s += __shfl_xor(s, off);
    __shared__ float red[4];
    const int wid = t >> 6, lane = t & 63;
    if (lane == 0) red[wid] = s;
    __syncthreads();
    s = red[0] + red[1] + red[2] + red[3];
    const float inv = 1.0f / s;
    float4 a, b;
    a.x = f[0] * inv; a.y = f[1] * inv; a.z = f[2] * inv; a.w = f[3] * inv;
    b.x = f[4] * inv; b.y = f[5] * inv; b.z = f[6] * inv; b.w = f[7] * inv;
    *(float4*)(o + t * 8)     = a;
    *(float4*)(o + t * 8 + 4) = b;
    bf16x8 w;
#pragma unroll
    for (int k = 0; k < 8; k++) w[k] = (bf16)(f[k] * inv);
    *(bf16x8*)(p + t * 8) = w;
}

extern "C" void kernel_launch(void* const* d_in, const int* in_sizes, int n_in,
                              void* d_out, int out_size, void* d_ws, size_t ws_size,
                              hipStream_t stream)
{
    const int B = 4, S = 2048, E = 1024;
    const float* X    = (const float*)d_in[0];   // [B,S,E]
    const float* W    = (const float*)d_in[1];   // [3E,E]
    const float* bias = (const float*)d_in[2];   // [3E]

    float* out0 = (float*)d_out;                  // [B,S,E]
    float* out1 = out0 + (long)B * S * E;         // [B,S,S]

    // ws layout (bytes):
    //   [ 0M, 48M)  qkvb bf16 [B*S, 3072]
    //   [48M, 64M)  Vt   bf16 [B][E][S]
    //   [64M, 96M)  Pu   bf16 [B][S][S]  (exp-scores; renormalized in place)
    //   Xb [64M,80M) and Wb [80M,86.3M) overlap Pu — dead before Pu is written.
    char* ws = (char*)d_ws;
    bf16* qkvb = (bf16*)(ws);
    bf16* Vt   = (bf16*)(ws + 50331648);
    bf16* Pu   = (bf16*)(ws + 67108864);
    bf16* Xb   = (bf16*)(ws + 67108864);
    bf16* Wb   = (bf16*)(ws + 83886080);

    f32_to_bf16<<<(long)B * S * E / 1024, 256, 0, stream>>>(X, Xb, (long)B * S * E);
    f32_to_bf16<<<(long)3 * E * E / 1024, 256, 0, stream>>>(W, Wb, (long)3 * E * E);

    // qkvb = bf16(X @ W^T + b)
    mfma_nt<MODE_QKV><<<dim3(3 * E / 128, B * S / 128, 1), 256, 0, stream>>>(
        Xb, Wb, bias, qkvb, E, E, E, 3 * E, 0, 0, 0, 1.0f);

    // Vt = V^T per batch
    transpose_v<<<dim3(S / 32, E / 32, B), 256, 0, stream>>>(qkvb + 2 * E, Vt);

    // Pu = bf16(exp(Q @ K^T / 32))
    mfma_nt<MODE_SCORES><<<dim3(S / 128, S / 128, B), 256, 0, stream>>>(
        qkvb, qkvb + E, nullptr, Pu, E, 3 * E, 3 * E, S,
        (long)S * 3 * E, (long)S * 3 * E, (long)S * S, 0.03125f);

    // out1 = Pu / rowsum  (fp32); Pu <- normalized bf16 in place
    norm_rows<<<B * S, 256, 0, stream>>>(Pu, out1);

    // out0 = P @ V  (= Pu @ Vt^T, NT)
    mfma_nt<MODE_PV><<<dim3(E / 128, S / 128, B), 256, 0, stream>>>(
        Pu, Vt, nullptr, out0, S, S, S, E,
        (long)S * S, (long)E * S, (long)S * E, 1.0f);
}